// Round 12
// baseline (191.903 us; speedup 1.0000x reference)
//
#include <hip/hip_runtime.h>

#define NSTREAMS 4
#define DIM 256
#define BM 16
#define NTHREADS 1024
#define TILES 8

typedef __attribute__((ext_vector_type(8))) short short8;
typedef __attribute__((ext_vector_type(4))) float f32x4;

// f32x4 -> packed bf16x4 via HW v_cvt_pk_bf16_f32 (RNE)
static __device__ __forceinline__ int2 f2bf4(float4 v) {
    unsigned int lo, hi;
    asm("v_cvt_pk_bf16_f32 %0, %1, %2" : "=v"(lo) : "v"(v.x), "v"(v.y));
    asm("v_cvt_pk_bf16_f32 %0, %1, %2" : "=v"(hi) : "v"(v.z), "v"(v.w));
    int2 r; r.x = (int)lo; r.y = (int)hi;
    return r;
}

// Block-uniform float -> SGPR (all lanes hold the same value).
static __device__ __forceinline__ float rfl(float x) {
    int i = __builtin_amdgcn_readfirstlane(__builtin_bit_cast(int, x));
    return __builtin_bit_cast(float, i);
}

// Block barrier that drains LDS ops only — does NOT drain vmcnt.
static __device__ __forceinline__ void barrier_lgkm() {
    asm volatile("s_waitcnt lgkmcnt(0)\n\ts_barrier" ::: "memory");
}

// MAX-OCCUPANCY variant: 2 blocks/CU x 16 waves = 32 waves/CU (100%).
// __launch_bounds__(1024, 8) pins VGPR <= 64: no W preload, no prefetch,
// no double-buffer — latency hiding comes from TLP (like the 6.3 TB/s
// copy/fill reference kernels), not per-wave ILP.
__global__ __launch_bounds__(NTHREADS, 8) void fused_kernel(
    const float* __restrict__ res,
    const float* __restrict__ Wb,
    const float* __restrict__ hres_l,
    const float* __restrict__ hpre_l,
    const float* __restrict__ hpost_l,
    float* __restrict__ out)
{
    __shared__ __align__(16) short bi_lds[BM][DIM + 8];   // 8.25 KB
    __shared__ __align__(16) float bo_lds[BM][DIM + 4];   // 16.25 KB

    const int t  = threadIdx.x;
    const int w  = t >> 6;    // wave id 0..15
    const int l  = t & 63;
    const int lr = l & 15;    // GEMM: batch row of acc
    const int lk = l >> 4;    // GEMM: k-block / d-subblock

    const long tile0 = (long)blockIdx.x * TILES;
    const long tstride = (long)BM * (NSTREAMS * DIM);        // 16384 floats
    // IO role: row w, d-slice l*4 -> every global access 1KB contiguous/wave
    const float* rl0 = res + (tile0 * BM + w) * (long)(NSTREAMS * DIM) + l * 4;
    float* ob0 = out + (tile0 * BM + w) * (long)(4 * DIM) + l * 4;
    // GEMM role: W row dcol
    const int dcol = w * 16 + lr;
    const float4* wrow4 = reinterpret_cast<const float4*>(Wb + dcol * DIM);

    // ---- wave-parallel Sinkhorn (4x4, 10 iters, tau=0.05); h -> SGPRs
    float hres[4][4];
    float hp0, hp1, hp2, hp3;
    float hq[4];
    {
        const int li = l & 15;
        float z = hres_l[li] * 20.0f;          // 1/tau = 20
        float uu = 0.f, vv = 0.f;
        const float logm = -logf(4.0f);
        #pragma unroll 1
        for (int it = 0; it < 10; ++it) {
            float tj = z + vv;
            float m = fmaxf(tj, __shfl_xor(tj, 1));
            m = fmaxf(m, __shfl_xor(m, 2));
            float e = expf(tj - m);
            float ss = e + __shfl_xor(e, 1);
            ss += __shfl_xor(ss, 2);
            uu = logm - (m + logf(ss));
            float ti2 = z + uu;
            float m2 = fmaxf(ti2, __shfl_xor(ti2, 4));
            m2 = fmaxf(m2, __shfl_xor(m2, 8));
            float e2 = expf(ti2 - m2);
            float s2 = e2 + __shfl_xor(e2, 4);
            s2 += __shfl_xor(s2, 8);
            vv = logm - (m2 + logf(s2));
        }
        float hval = expf(z + uu + vv) * 4.0f;
        #pragma unroll
        for (int s = 0; s < 4; ++s)
            #pragma unroll
            for (int tt = 0; tt < 4; ++tt)
                hres[s][tt] = rfl(__shfl(hval, s * 4 + tt));
        float p0 = hpre_l[0], p1 = hpre_l[1], p2 = hpre_l[2], p3 = hpre_l[3];
        float pm = fmaxf(fmaxf(p0, p1), fmaxf(p2, p3));
        float e0 = expf(p0 - pm), e1 = expf(p1 - pm), e2 = expf(p2 - pm), e3 = expf(p3 - pm);
        float es = e0 + e1 + e2 + e3;
        hp0 = rfl(e0 / es); hp1 = rfl(e1 / es); hp2 = rfl(e2 / es); hp3 = rfl(e3 / es);
        float q0 = hpost_l[0], q1 = hpost_l[1], q2 = hpost_l[2], q3 = hpost_l[3];
        float qm = fmaxf(fmaxf(q0, q1), fmaxf(q2, q3));
        float f0 = expf(q0 - qm), f1 = expf(q1 - qm), f2 = expf(q2 - qm), f3 = expf(q3 - qm);
        float fs = f0 + f1 + f2 + f3;
        hq[0] = rfl(f0 / fs); hq[1] = rfl(f1 / fs); hq[2] = rfl(f2 / fs); hq[3] = rfl(f3 / fs);
    }

    for (int ti = 0; ti < TILES; ++ti) {
        // ---- load raw (1KB contiguous per wave per instruction)
        const float* rb = rl0 + ti * tstride;
        float4 R0 = *reinterpret_cast<const float4*>(rb + 0 * DIM);
        float4 R1 = *reinterpret_cast<const float4*>(rb + 1 * DIM);
        float4 R2 = *reinterpret_cast<const float4*>(rb + 2 * DIM);
        float4 R3 = *reinterpret_cast<const float4*>(rb + 3 * DIM);

        // ---- stage bi (in-lane; vmcnt(0) wait here, covered by TLP)
        {
            float4 bi;
            bi.x = hp0 * R0.x + hp1 * R1.x + hp2 * R2.x + hp3 * R3.x;
            bi.y = hp0 * R0.y + hp1 * R1.y + hp2 * R2.y + hp3 * R3.y;
            bi.z = hp0 * R0.z + hp1 * R1.z + hp2 * R2.z + hp3 * R3.z;
            bi.w = hp0 * R0.w + hp1 * R1.w + hp2 * R2.w + hp3 * R3.w;
            *reinterpret_cast<int2*>(&bi_lds[w][l * 4]) = f2bf4(bi);
        }
        barrier_lgkm();   // bi visible (prev tile's bi reads all pre-barrier2)

        // ---- GEMM: bi from LDS, W f32 from L2 converted in-flight
        {
            f32x4 acc = {0.f, 0.f, 0.f, 0.f};
            #pragma unroll
            for (int kk = 0; kk < 8; ++kk) {
                short8 bfrag = *reinterpret_cast<const short8*>(&bi_lds[lr][kk * 32 + lk * 8]);
                float4 wa = wrow4[kk * 8 + lk * 2];
                float4 wb2 = wrow4[kk * 8 + lk * 2 + 1];
                union { int4 i; short8 s; } u8;
                int2 lo = f2bf4(wa);
                int2 hi = f2bf4(wb2);
                u8.i.x = lo.x; u8.i.y = lo.y; u8.i.z = hi.x; u8.i.w = hi.y;
                acc = __builtin_amdgcn_mfma_f32_16x16x32_bf16(u8.s, bfrag, acc, 0, 0, 0);
            }
            *reinterpret_cast<f32x4*>(&bo_lds[lr][(w << 4) + (lk << 2)]) = acc;
        }
        barrier_lgkm();   // bo visible; bi reads drained

        // ---- epilogue: bo from LDS + rs from raw regs; 1KB contiguous stores
        {
            f32x4 bo = *reinterpret_cast<const f32x4*>(&bo_lds[w][l * 4]);
            float* ob = ob0 + ti * (long)(BM * 4 * DIM);
            #pragma unroll
            for (int tt = 0; tt < 4; ++tt) {
                float4 o;
                o.x = hq[tt] * bo[0] + hres[0][tt] * R0.x + hres[1][tt] * R1.x + hres[2][tt] * R2.x + hres[3][tt] * R3.x;
                o.y = hq[tt] * bo[1] + hres[0][tt] * R0.y + hres[1][tt] * R1.y + hres[2][tt] * R2.y + hres[3][tt] * R3.y;
                o.z = hq[tt] * bo[2] + hres[0][tt] * R0.z + hres[1][tt] * R1.z + hres[2][tt] * R2.z + hres[3][tt] * R3.z;
                o.w = hq[tt] * bo[3] + hres[0][tt] * R0.w + hres[1][tt] * R1.w + hres[2][tt] * R2.w + hres[3][tt] * R3.w;
                *reinterpret_cast<float4*>(ob + tt * DIM) = o;
            }
        }
        // bo(ti) reads complete before barrier1(ti+1); bo(ti+1) written after
        // it -> single bo buffer safe. Same for bi. 2 barriers/tile total.
    }
}

extern "C" void kernel_launch(void* const* d_in, const int* in_sizes, int n_in,
                              void* d_out, int out_size, void* d_ws, size_t ws_size,
                              hipStream_t stream) {
    const float* res     = (const float*)d_in[0];
    const float* hres_l  = (const float*)d_in[1];
    const float* hpre_l  = (const float*)d_in[2];
    const float* hpost_l = (const float*)d_in[3];
    const float* Wb      = (const float*)d_in[4];
    float* out = (float*)d_out;

    const int Btot = in_sizes[0] / (NSTREAMS * DIM);   // 65536
    const int grid = Btot / (BM * TILES);              // 512 = 2 blocks/CU

    fused_kernel<<<grid, NTHREADS, 0, stream>>>(
        res, Wb, hres_l, hpre_l, hpost_l, out);
}

// Round 13
// 114.125 us; speedup vs baseline: 1.6815x; 1.6815x over previous
//
#include <hip/hip_runtime.h>

#define NSTREAMS 4
#define DIM 256
#define BM 16
#define NTHREADS 1024
#define TILES 16

typedef __attribute__((ext_vector_type(8))) short short8;
typedef __attribute__((ext_vector_type(4))) float f32x4;

// f32x4 -> packed bf16x4 via HW v_cvt_pk_bf16_f32 (RNE)
static __device__ __forceinline__ int2 f2bf4(float4 v) {
    unsigned int lo, hi;
    asm("v_cvt_pk_bf16_f32 %0, %1, %2" : "=v"(lo) : "v"(v.x), "v"(v.y));
    asm("v_cvt_pk_bf16_f32 %0, %1, %2" : "=v"(hi) : "v"(v.z), "v"(v.w));
    int2 r; r.x = (int)lo; r.y = (int)hi;
    return r;
}

// Block-uniform float -> SGPR (all lanes hold the same value).
static __device__ __forceinline__ float rfl(float x) {
    int i = __builtin_amdgcn_readfirstlane(__builtin_bit_cast(int, x));
    return __builtin_bit_cast(float, i);
}

// Block barrier that drains LDS ops only — does NOT drain vmcnt, so global
// loads issued before it stay in flight across the barrier (T4 discipline).
static __device__ __forceinline__ void barrier_lgkm() {
    asm volatile("s_waitcnt lgkmcnt(0)\n\ts_barrier" ::: "memory");
}

__global__ __launch_bounds__(NTHREADS, 1) void fused_kernel(
    const float* __restrict__ res,
    const float* __restrict__ Wb,
    const float* __restrict__ hres_l,
    const float* __restrict__ hpre_l,
    const float* __restrict__ hpost_l,
    float* __restrict__ out)
{
    // SESSION-BEST STRUCTURE (R9, 114.4 us):
    //  - single launch; Sinkhorn wave-parallel in-kernel; h in SGPRs
    //  - W register-resident (32 VGPR/lane, loaded once from L2/L3)
    //  - WAVE-CONTIGUOUS globals: wave w owns batch-row w, lane l owns
    //    d-slice l*4 -> every global ld/st is 1KB contiguous per wave
    //  - bi computed in-lane -> 8B LDS write; GEMM reads bi cross-wave;
    //    acc returns via f32 bo_lds (+4 pad); rs-part exact f32 in regs
    //  - depth-1 prefetch (A/B reg sets), 2 lgkm-only barriers/tile
    __shared__ __align__(16) short bi_lds[2][BM][DIM + 8];   // 2 x 8.25 KB
    __shared__ __align__(16) float bo_lds[BM][DIM + 4];      // 16.25 KB

    const int t  = threadIdx.x;
    const int w  = t >> 6;    // wave id 0..15
    const int l  = t & 63;
    const int lr = l & 15;    // GEMM: batch row of acc
    const int lk = l >> 4;    // GEMM: k-block / d-subblock

    const long tile0 = (long)blockIdx.x * TILES;
    const long tstride = (long)BM * (NSTREAMS * DIM);        // 16384 floats
    // load/store role: row w, d-slice l*4 (1KB contiguous per wave per instr)
    const float* rl0 = res + (tile0 * BM + w) * (long)(NSTREAMS * DIM) + l * 4;
    float* ob0 = out + (tile0 * BM + w) * (long)(4 * DIM) + l * 4;
    // GEMM role: W row dcol
    const int dcol = w * 16 + lr;

    // ---- issue tile-0 res loads FIRST (longest latency)
    float4 A0, A1, A2, A3;
    A0 = *reinterpret_cast<const float4*>(rl0 + 0 * DIM);
    A1 = *reinterpret_cast<const float4*>(rl0 + 1 * DIM);
    A2 = *reinterpret_cast<const float4*>(rl0 + 2 * DIM);
    A3 = *reinterpret_cast<const float4*>(rl0 + 3 * DIM);

    // ---- issue W row loads (f32, L2/L3-resident after first touch)
    const float4* wrow4 = reinterpret_cast<const float4*>(Wb + dcol * DIM);
    float4 wfa[8], wfb[8];
    #pragma unroll
    for (int kk = 0; kk < 8; ++kk) {
        wfa[kk] = wrow4[kk * 8 + lk * 2];
        wfb[kk] = wrow4[kk * 8 + lk * 2 + 1];
    }

    // ---- wave-parallel Sinkhorn (4x4, 10 iters, tau=0.05), every wave
    //      redundantly; lane l&15 owns z[i][j] with i=bits3:2, j=bits1:0.
    float hres[4][4];
    float hp0, hp1, hp2, hp3;
    float hq[4];
    {
        const int li = l & 15;
        float z = hres_l[li] * 20.0f;          // 1/tau = 20
        float uu = 0.f, vv = 0.f;
        const float logm = -logf(4.0f);
        #pragma unroll 1
        for (int it = 0; it < 10; ++it) {
            float tj = z + vv;
            float m = fmaxf(tj, __shfl_xor(tj, 1));
            m = fmaxf(m, __shfl_xor(m, 2));
            float e = expf(tj - m);
            float ss = e + __shfl_xor(e, 1);
            ss += __shfl_xor(ss, 2);
            uu = logm - (m + logf(ss));
            float ti2 = z + uu;
            float m2 = fmaxf(ti2, __shfl_xor(ti2, 4));
            m2 = fmaxf(m2, __shfl_xor(m2, 8));
            float e2 = expf(ti2 - m2);
            float s2 = e2 + __shfl_xor(e2, 4);
            s2 += __shfl_xor(s2, 8);
            vv = logm - (m2 + logf(s2));
        }
        float hval = expf(z + uu + vv) * 4.0f;
        #pragma unroll
        for (int s = 0; s < 4; ++s)
            #pragma unroll
            for (int tt = 0; tt < 4; ++tt)
                hres[s][tt] = rfl(__shfl(hval, s * 4 + tt));
        float p0 = hpre_l[0], p1 = hpre_l[1], p2 = hpre_l[2], p3 = hpre_l[3];
        float pm = fmaxf(fmaxf(p0, p1), fmaxf(p2, p3));
        float e0 = expf(p0 - pm), e1 = expf(p1 - pm), e2 = expf(p2 - pm), e3 = expf(p3 - pm);
        float es = e0 + e1 + e2 + e3;
        hp0 = rfl(e0 / es); hp1 = rfl(e1 / es); hp2 = rfl(e2 / es); hp3 = rfl(e3 / es);
        float q0 = hpost_l[0], q1 = hpost_l[1], q2 = hpost_l[2], q3 = hpost_l[3];
        float qm = fmaxf(fmaxf(q0, q1), fmaxf(q2, q3));
        float f0 = expf(q0 - qm), f1 = expf(q1 - qm), f2 = expf(q2 - qm), f3 = expf(q3 - qm);
        float fs = f0 + f1 + f2 + f3;
        hq[0] = rfl(f0 / fs); hq[1] = rfl(f1 / fs); hq[2] = rfl(f2 / fs); hq[3] = rfl(f3 / fs);
    }

    // ---- convert W f32 -> bf16 fragments (register-resident for all tiles)
    short8 wf[8];
    #pragma unroll
    for (int kk = 0; kk < 8; ++kk) {
        union { int4 i; short8 s; } u8;
        int2 lo = f2bf4(wfa[kk]);
        int2 hi = f2bf4(wfb[kk]);
        u8.i.x = lo.x; u8.i.y = lo.y; u8.i.z = hi.x; u8.i.w = hi.y;
        wf[kk] = u8.s;
    }

    // ---- stage bi(0) into buf0 (in-lane: all 4 streams are local)
    {
        float4 bi;
        bi.x = hp0 * A0.x + hp1 * A1.x + hp2 * A2.x + hp3 * A3.x;
        bi.y = hp0 * A0.y + hp1 * A1.y + hp2 * A2.y + hp3 * A3.y;
        bi.z = hp0 * A0.z + hp1 * A1.z + hp2 * A2.z + hp3 * A3.z;
        bi.w = hp0 * A0.w + hp1 * A1.w + hp2 * A2.w + hp3 * A3.w;
        *reinterpret_cast<int2*>(&bi_lds[0][w][l * 4]) = f2bf4(bi);
    }
    // ---- issue tile-1 loads into B (in flight across tile 0's GEMM)
    float4 B0, B1, B2, B3;
    B0 = *reinterpret_cast<const float4*>(rl0 + tstride + 0 * DIM);
    B1 = *reinterpret_cast<const float4*>(rl0 + tstride + 1 * DIM);
    B2 = *reinterpret_cast<const float4*>(rl0 + tstride + 2 * DIM);
    B3 = *reinterpret_cast<const float4*>(rl0 + tstride + 3 * DIM);

    barrier_lgkm();   // bi(0) visible

    for (int ti = 0; ti < TILES; ti += 2) {
        // ======== even half: GEMM buf0; epi from A; stage B->buf1 ===========
        {
            f32x4 acc = {0.f, 0.f, 0.f, 0.f};
            #pragma unroll
            for (int kk = 0; kk < 8; ++kk) {
                short8 bfrag = *reinterpret_cast<const short8*>(&bi_lds[0][lr][kk * 32 + lk * 8]);
                acc = __builtin_amdgcn_mfma_f32_16x16x32_bf16(wf[kk], bfrag, acc, 0, 0, 0);
            }
            *reinterpret_cast<f32x4*>(&bo_lds[lr][(w << 4) + (lk << 2)]) = acc;
            barrier_lgkm();   // mid: bo visible; buf0 reads drained
            {   // epilogue: wave-contiguous 1KB stores, rs-part exact f32
                f32x4 bo = *reinterpret_cast<const f32x4*>(&bo_lds[w][l * 4]);
                float* ob = ob0 + ti * (long)(BM * 4 * DIM);
                #pragma unroll
                for (int tt = 0; tt < 4; ++tt) {
                    float4 o;
                    o.x = hq[tt] * bo[0] + hres[0][tt] * A0.x + hres[1][tt] * A1.x + hres[2][tt] * A2.x + hres[3][tt] * A3.x;
                    o.y = hq[tt] * bo[1] + hres[0][tt] * A0.y + hres[1][tt] * A1.y + hres[2][tt] * A2.y + hres[3][tt] * A3.y;
                    o.z = hq[tt] * bo[2] + hres[0][tt] * A0.z + hres[1][tt] * A1.z + hres[2][tt] * A2.z + hres[3][tt] * A3.z;
                    o.w = hq[tt] * bo[3] + hres[0][tt] * A0.w + hres[1][tt] * A1.w + hres[2][tt] * A2.w + hres[3][tt] * A3.w;
                    *reinterpret_cast<float4*>(ob + tt * DIM) = o;
                }
            }
            if (ti + 2 < TILES) {   // issue A <- res(ti+2) (A free after epi)
                const float* rb = rl0 + (ti + 2) * tstride;
                A0 = *reinterpret_cast<const float4*>(rb + 0 * DIM);
                A1 = *reinterpret_cast<const float4*>(rb + 1 * DIM);
                A2 = *reinterpret_cast<const float4*>(rb + 2 * DIM);
                A3 = *reinterpret_cast<const float4*>(rb + 3 * DIM);
            }
            __builtin_amdgcn_sched_barrier(0);   // pin issue before stage VALU
            {   // stage bi(ti+1) from B -> buf1 (vmcnt wait for B lands here)
                float4 bi;
                bi.x = hp0 * B0.x + hp1 * B1.x + hp2 * B2.x + hp3 * B3.x;
                bi.y = hp0 * B0.y + hp1 * B1.y + hp2 * B2.y + hp3 * B3.y;
                bi.z = hp0 * B0.z + hp1 * B1.z + hp2 * B2.z + hp3 * B3.z;
                bi.w = hp0 * B0.w + hp1 * B1.w + hp2 * B2.w + hp3 * B3.w;
                *reinterpret_cast<int2*>(&bi_lds[1][w][l * 4]) = f2bf4(bi);
            }
            barrier_lgkm();   // end: buf1 visible; bo reads drained
        }
        // ======== odd half: GEMM buf1; epi from B; stage A->buf0 ============
        {
            f32x4 acc = {0.f, 0.f, 0.f, 0.f};
            #pragma unroll
            for (int kk = 0; kk < 8; ++kk) {
                short8 bfrag = *reinterpret_cast<const short8*>(&bi_lds[1][lr][kk * 32 + lk * 8]);
                acc = __builtin_amdgcn_mfma_f32_16x16x32_bf16(wf[kk], bfrag, acc, 0, 0, 0);
            }
            *reinterpret_cast<f32x4*>(&bo_lds[lr][(w << 4) + (lk << 2)]) = acc;
            barrier_lgkm();   // mid
            {
                f32x4 bo = *reinterpret_cast<const f32x4*>(&bo_lds[w][l * 4]);
                float* ob = ob0 + (ti + 1) * (long)(BM * 4 * DIM);
                #pragma unroll
                for (int tt = 0; tt < 4; ++tt) {
                    float4 o;
                    o.x = hq[tt] * bo[0] + hres[0][tt] * B0.x + hres[1][tt] * B1.x + hres[2][tt] * B2.x + hres[3][tt] * B3.x;
                    o.y = hq[tt] * bo[1] + hres[0][tt] * B0.y + hres[1][tt] * B1.y + hres[2][tt] * B2.y + hres[3][tt] * B3.y;
                    o.z = hq[tt] * bo[2] + hres[0][tt] * B0.z + hres[1][tt] * B1.z + hres[2][tt] * B2.z + hres[3][tt] * B3.z;
                    o.w = hq[tt] * bo[3] + hres[0][tt] * B0.w + hres[1][tt] * B1.w + hres[2][tt] * B2.w + hres[3][tt] * B3.w;
                    *reinterpret_cast<float4*>(ob + tt * DIM) = o;
                }
            }
            if (ti + 3 < TILES) {   // issue B <- res(ti+3)
                const float* rb = rl0 + (ti + 3) * tstride;
                B0 = *reinterpret_cast<const float4*>(rb + 0 * DIM);
                B1 = *reinterpret_cast<const float4*>(rb + 1 * DIM);
                B2 = *reinterpret_cast<const float4*>(rb + 2 * DIM);
                B3 = *reinterpret_cast<const float4*>(rb + 3 * DIM);
            }
            __builtin_amdgcn_sched_barrier(0);
            if (ti + 2 < TILES) {   // stage bi(ti+2) from A -> buf0
                float4 bi;
                bi.x = hp0 * A0.x + hp1 * A1.x + hp2 * A2.x + hp3 * A3.x;
                bi.y = hp0 * A0.y + hp1 * A1.y + hp2 * A2.y + hp3 * A3.y;
                bi.z = hp0 * A0.z + hp1 * A1.z + hp2 * A2.z + hp3 * A3.z;
                bi.w = hp0 * A0.w + hp1 * A1.w + hp2 * A2.w + hp3 * A3.w;
                *reinterpret_cast<int2*>(&bi_lds[0][w][l * 4]) = f2bf4(bi);
            }
            barrier_lgkm();   // end
        }
    }
}

extern "C" void kernel_launch(void* const* d_in, const int* in_sizes, int n_in,
                              void* d_out, int out_size, void* d_ws, size_t ws_size,
                              hipStream_t stream) {
    const float* res     = (const float*)d_in[0];
    const float* hres_l  = (const float*)d_in[1];
    const float* hpre_l  = (const float*)d_in[2];
    const float* hpost_l = (const float*)d_in[3];
    const float* Wb      = (const float*)d_in[4];
    float* out = (float*)d_out;

    const int Btot = in_sizes[0] / (NSTREAMS * DIM);   // 65536
    const int grid = Btot / (BM * TILES);              // 256 = 1 block/CU

    fused_kernel<<<grid, NTHREADS, 0, stream>>>(
        res, Wb, hres_l, hpre_l, hpost_l, out);
}